// Round 11
// baseline (280.003 us; speedup 1.0000x reference)
//
#include <hip/hip_runtime.h>
#include <stdint.h>
#include <math.h>

// Problem constants (from reference: B=2048, D=512, TAU=0.5)
#define DIM       512
#define NROWS     8192      // 4*B
#define HALF_ROWS 4096      // 2*B
#define TILE      128
#define NT        64        // 8192/128 tiles per side
#define NTRI      2080      // live upper-triangle tiles (completion target)

typedef float  floatx4 __attribute__((ext_vector_type(4)));
typedef __bf16 bf16x8  __attribute__((ext_vector_type(8)));

// L2-normalize rows of [emb_i; emb_j] -> bf16 rep[8192][512]; also zero ws.
__global__ __launch_bounds__(256) void normalize_kernel(
    const float* __restrict__ emb_i, const float* __restrict__ emb_j,
    unsigned short* __restrict__ rep, double* __restrict__ ws)
{
    if (blockIdx.x == 0 && threadIdx.x == 0) {
        ws[0] = 0.0; ws[1] = 0.0;
        ((unsigned long long*)ws)[2] = 0ull;   // completion counter
    }
    const int wave = threadIdx.x >> 6;
    const int lane = threadIdx.x & 63;
    const int row  = blockIdx.x * 4 + wave;
    const float* src = (row < HALF_ROWS) ? (emb_i + (size_t)row * DIM)
                                         : (emb_j + (size_t)(row - HALF_ROWS) * DIM);
    const int c = lane * 8;
    float4 v0 = *(const float4*)(src + c);
    float4 v1 = *(const float4*)(src + c + 4);
    float s = v0.x*v0.x + v0.y*v0.y + v0.z*v0.z + v0.w*v0.w
            + v1.x*v1.x + v1.y*v1.y + v1.z*v1.z + v1.w*v1.w;
    #pragma unroll
    for (int off = 32; off; off >>= 1) s += __shfl_xor(s, off, 64);
    const float inv = 1.0f / fmaxf(sqrtf(s), 1e-12f);
    float f[8] = {v0.x*inv, v0.y*inv, v0.z*inv, v0.w*inv,
                  v1.x*inv, v1.y*inv, v1.z*inv, v1.w*inv};
    union { unsigned short h[8]; uint4 u; } pk;
    #pragma unroll
    for (int t = 0; t < 8; ++t) {   // fp32 -> bf16 RNE
        uint32_t b = __float_as_uint(f[t]);
        b += 0x7FFFu + ((b >> 16) & 1u);
        pk.h[t] = (unsigned short)(b >> 16);
    }
    *(uint4*)(rep + (size_t)row * DIM + c) = pk.u;
}

// Barrier-free direct-from-L2 Gram tile. Each of the 4 waves owns one 64x64
// quadrant INDEPENDENTLY: MFMA A/B fragments are loaded straight from global
// memory into VGPRs (no LDS operands, no staging, no K-loop barriers).
// Fragment load = 16 rows x 64 B contiguous = 16 fully-utilized cache lines
// per wave -- the 16x16x32 operand layout makes direct loads line-perfect.
// Independent wave-streams replace the ~2 block-convoys of the LDS variants
// (which pinned MfmaUtil at 12-15% across R0-R9).
// NOTE: no min-waves clause -- forcing a 128-VGPR cap risks the R3 spill
// pathology; natural allocation (~110-140 VGPR) gives 3-4 blocks/CU anyway.
__global__ __launch_bounds__(256) void gram_kernel(
    const unsigned short* __restrict__ rep, double* __restrict__ ws,
    float* __restrict__ out)
{
    __shared__ float red[8];

    const int bj = blockIdx.x, bi = blockIdx.y;   // R0-proven square grid
    if (bj < bi) return;                          // dead blocks stagger dispatch

    const int tid  = threadIdx.x;
    const int wave = tid >> 6, lane = tid & 63;
    const int wm = wave >> 1, wn = wave & 1;      // 2x2 waves of 64x64 quadrants
    const int m = lane & 15, quad = lane >> 4;    // MFMA fragment coords
    const int i0 = bi * TILE, j0 = bj * TILE;

    // Per-lane base pointers: lane l of fragment mt reads
    // A[i0 + wm*64 + mt*16 + (l&15)][k0 + (l>>4)*8 .. +7]  (16 B contiguous),
    // identical per-lane data mapping to the LDS reads verified in R0-R9.
    const unsigned short* pa = rep + (size_t)(i0 + wm * 64 + m) * DIM + quad * 8;
    const unsigned short* pb = rep + (size_t)(j0 + wn * 64 + m) * DIM + quad * 8;

    floatx4 acc[4][4];
    #pragma unroll
    for (int a2 = 0; a2 < 4; ++a2)
        #pragma unroll
        for (int b2 = 0; b2 < 4; ++b2)
            #pragma unroll
            for (int e = 0; e < 4; ++e) acc[a2][b2][e] = 0.0f;

    // K-loop: 16 iters, each 8 direct global loads (VGPR) + 16 MFMA.
    // No barriers, no LDS: each wave is an independent load->MFMA stream;
    // latency hides across the resident wave-streams per CU.
    for (int k0 = 0; k0 < DIM; k0 += 32) {
        bf16x8 af[4], bfr[4];
        #pragma unroll
        for (int mt = 0; mt < 4; ++mt)
            af[mt] = *(const bf16x8*)(pa + (size_t)mt * 16 * DIM + k0);
        #pragma unroll
        for (int nt = 0; nt < 4; ++nt)
            bfr[nt] = *(const bf16x8*)(pb + (size_t)nt * 16 * DIM + k0);
        #pragma unroll
        for (int mt = 0; mt < 4; ++mt)
            #pragma unroll
            for (int nt = 0; nt < 4; ++nt)
                acc[mt][nt] = __builtin_amdgcn_mfma_f32_16x16x32_bf16(
                    af[mt], bfr[nt], acc[mt][nt], 0, 0, 0);
    }

    // Epilogue: exp(sim/tau) = exp2(sim * 2/ln2); band + total sums.
    // 16x16 C/D layout: col = lane&15, row = (lane>>4)*4 + reg.
    float s_all = 0.0f, s_pos = 0.0f;
    const float LOG2E2 = 2.885390081777927f;  // 2 / ln(2)
    #pragma unroll
    for (int mt = 0; mt < 4; ++mt) {
        const int ibase = i0 + wm * 64 + mt * 16 + quad * 4;
        #pragma unroll
        for (int nt = 0; nt < 4; ++nt) {
            const int j = j0 + wn * 64 + nt * 16 + m;
            const floatx4 v = acc[mt][nt];
            #pragma unroll
            for (int r2 = 0; r2 < 4; ++r2) {
                const int i = ibase + r2;
                const float ex = exp2f(v[r2] * LOG2E2);
                if (i != j) s_all += ex;
                const int d = j - i;          // upper triangle: positive bands
                if (d == 2048 || d == 4096 || d == 6144) s_pos += ex;
            }
        }
    }
    #pragma unroll
    for (int off = 32; off; off >>= 1) {
        s_all += __shfl_xor(s_all, off, 64);
        s_pos += __shfl_xor(s_pos, off, 64);
    }
    if (lane == 0) { red[wave] = s_all; red[4 + wave] = s_pos; }
    __syncthreads();
    if (tid == 0) {
        const float wgt = (bi == bj) ? 1.0f : 2.0f;  // off-diag covers transpose
        const float ta = (red[0] + red[1] + red[2] + red[3]) * wgt;
        const float tp = (red[4] + red[5] + red[6] + red[7]) * wgt;
        atomicAdd(&ws[0], (double)ta);
        atomicAdd(&ws[1], (double)tp);
        __threadfence();
        unsigned* ctr = (unsigned*)(ws + 2);
        if (atomicAdd(ctr, 1u) == NTRI - 1) {     // last live tile: finalize
            __threadfence();
            const double nom = atomicAdd(&ws[1], 0.0);
            const double den = atomicAdd(&ws[0], 0.0) - nom;
            out[0] = (float)(-log(nom / den) / (double)NROWS);
        }
    }
}

extern "C" void kernel_launch(void* const* d_in, const int* in_sizes, int n_in,
                              void* d_out, int out_size, void* d_ws, size_t ws_size,
                              hipStream_t stream) {
    const float* emb_i = (const float*)d_in[0];
    const float* emb_j = (const float*)d_in[1];
    float* out = (float*)d_out;
    double* ws = (double*)d_ws;                                   // accums + counter
    unsigned short* rep = (unsigned short*)((char*)d_ws + 256);   // bf16 [8192][512]

    hipLaunchKernelGGL(normalize_kernel, dim3(NROWS / 4), dim3(256), 0, stream,
                       emb_i, emb_j, rep, ws);
    hipLaunchKernelGGL(gram_kernel, dim3(NT, NT), dim3(256), 0, stream, rep, ws, out);
}

// Round 12
// 182.324 us; speedup vs baseline: 1.5357x; 1.5357x over previous
//
#include <hip/hip_runtime.h>
#include <stdint.h>
#include <math.h>

// Problem constants (from reference: B=2048, D=512, TAU=0.5)
#define DIM       512
#define NROWS     8192      // 4*B
#define HALF_ROWS 4096      // 2*B
#define TILE      128
#define BK        32
#define NT        64        // 8192/128 tiles per side
#define NTRI      2080      // live upper-triangle tiles (completion target)

typedef float  floatx4 __attribute__((ext_vector_type(4)));
typedef __bf16 bf16x8  __attribute__((ext_vector_type(8)));

__device__ __forceinline__ void async_copy16(const unsigned short* g, unsigned short* l) {
    __builtin_amdgcn_global_load_lds(
        (const __attribute__((address_space(1))) uint32_t*)(g),
        (__attribute__((address_space(3))) uint32_t*)(l),
        16, 0, 0);
}

// L2-normalize rows of [emb_i; emb_j] -> bf16 rep[8192][512]; also zero ws
// (init fused here: saves one launch, ~15-20 us of gap per R1's measurement).
__global__ __launch_bounds__(256) void normalize_kernel(
    const float* __restrict__ emb_i, const float* __restrict__ emb_j,
    unsigned short* __restrict__ rep, double* __restrict__ ws)
{
    if (blockIdx.x == 0 && threadIdx.x == 0) {
        ws[0] = 0.0; ws[1] = 0.0;
        ((unsigned long long*)ws)[2] = 0ull;   // completion counter
    }
    const int wave = threadIdx.x >> 6;
    const int lane = threadIdx.x & 63;
    const int row  = blockIdx.x * 4 + wave;
    const float* src = (row < HALF_ROWS) ? (emb_i + (size_t)row * DIM)
                                         : (emb_j + (size_t)(row - HALF_ROWS) * DIM);
    const int c = lane * 8;
    float4 v0 = *(const float4*)(src + c);
    float4 v1 = *(const float4*)(src + c + 4);
    float s = v0.x*v0.x + v0.y*v0.y + v0.z*v0.z + v0.w*v0.w
            + v1.x*v1.x + v1.y*v1.y + v1.z*v1.z + v1.w*v1.w;
    #pragma unroll
    for (int off = 32; off; off >>= 1) s += __shfl_xor(s, off, 64);
    const float inv = 1.0f / fmaxf(sqrtf(s), 1e-12f);
    float f[8] = {v0.x*inv, v0.y*inv, v0.z*inv, v0.w*inv,
                  v1.x*inv, v1.y*inv, v1.z*inv, v1.w*inv};
    union { unsigned short h[8]; uint4 u; } pk;
    #pragma unroll
    for (int t = 0; t < 8; ++t) {   // fp32 -> bf16 RNE
        uint32_t b = __float_as_uint(f[t]);
        b += 0x7FFFu + ((b >> 16) & 1u);
        pk.h[t] = (unsigned short)(b >> 16);
    }
    *(uint4*)(rep + (size_t)row * DIM + c) = pk.u;
}

// The session champion gram, byte-for-byte (R0 structure; won the R8 A/B and
// beat 8-phase/dbuf/swizzle/tournament/direct-load across R1-R11):
// square 2D grid with early-exit dead blocks (load-bearing: compact and
// tournament grids measured 30%+ slower with the same inner loop), BK=32,
// linear LDS (4-way bank aliasing measured benign), plain __syncthreads.
// Only change vs R0: finalize fused via completion counter (saves a launch).
__global__ __launch_bounds__(256) void gram_kernel(
    const unsigned short* __restrict__ rep, double* __restrict__ ws,
    float* __restrict__ out)
{
    const int bj = blockIdx.x, bi = blockIdx.y;
    if (bj < bi) return;

    __shared__ unsigned short As[TILE * BK];   // 8 KB, row-major [128][32]
    __shared__ unsigned short Bs[TILE * BK];   // 8 KB
    __shared__ float red[8];

    const int tid  = threadIdx.x;
    const int wave = tid >> 6, lane = tid & 63;
    const int wm = wave >> 1, wn = wave & 1;   // 2x2 waves of 64x64 quadrants
    const int m = lane & 15, quad = lane >> 4; // MFMA fragment coords

    floatx4 acc[4][4];
    #pragma unroll
    for (int a = 0; a < 4; ++a)
        #pragma unroll
        for (int b = 0; b < 4; ++b)
            #pragma unroll
            for (int e = 0; e < 4; ++e) acc[a][b][e] = 0.0f;

    const int i0 = bi * TILE, j0 = bj * TILE;

    for (int k0 = 0; k0 < DIM; k0 += BK) {
        // Stage A (rows i0..i0+127) and B (rows j0..j0+127), 32 cols each,
        // via direct global->LDS DMA (16 B per lane, lane-contiguous).
        #pragma unroll
        for (int r = 0; r < 2; ++r) {
            const int chunk = r * 256 + tid;          // 512 chunks of 16 B
            const int row   = chunk >> 2;             // 4 chunks per 32-col row
            const int cc    = (chunk & 3) * 8;
            async_copy16(rep + (size_t)(i0 + row) * DIM + k0 + cc, As + chunk * 8);
            async_copy16(rep + (size_t)(j0 + row) * DIM + k0 + cc, Bs + chunk * 8);
        }
        __syncthreads();

        bf16x8 af[4], bfr[4];
        #pragma unroll
        for (int mt = 0; mt < 4; ++mt)
            af[mt] = *(const bf16x8*)(As + (wm * 64 + mt * 16 + m) * BK + quad * 8);
        #pragma unroll
        for (int nt = 0; nt < 4; ++nt)
            bfr[nt] = *(const bf16x8*)(Bs + (wn * 64 + nt * 16 + m) * BK + quad * 8);
        #pragma unroll
        for (int mt = 0; mt < 4; ++mt)
            #pragma unroll
            for (int nt = 0; nt < 4; ++nt)
                acc[mt][nt] = __builtin_amdgcn_mfma_f32_16x16x32_bf16(
                    af[mt], bfr[nt], acc[mt][nt], 0, 0, 0);
        __syncthreads();
    }

    // Epilogue: exp(sim/tau) = exp2(sim * 2/ln2); band + total sums.
    // 16x16 C/D layout: col = lane&15, row = (lane>>4)*4 + reg.
    float s_all = 0.0f, s_pos = 0.0f;
    const float LOG2E2 = 2.885390081777927f;  // 2 / ln(2)
    #pragma unroll
    for (int mt = 0; mt < 4; ++mt) {
        const int ibase = i0 + wm * 64 + mt * 16 + quad * 4;
        #pragma unroll
        for (int nt = 0; nt < 4; ++nt) {
            const int j = j0 + wn * 64 + nt * 16 + m;
            const floatx4 v = acc[mt][nt];
            #pragma unroll
            for (int r2 = 0; r2 < 4; ++r2) {
                const int i = ibase + r2;
                const float ex = exp2f(v[r2] * LOG2E2);
                if (i != j) s_all += ex;
                const int d = j - i;          // upper triangle: positive bands
                if (d == 2048 || d == 4096 || d == 6144) s_pos += ex;
            }
        }
    }
    #pragma unroll
    for (int off = 32; off; off >>= 1) {
        s_all += __shfl_xor(s_all, off, 64);
        s_pos += __shfl_xor(s_pos, off, 64);
    }
    if (lane == 0) { red[wave] = s_all; red[4 + wave] = s_pos; }
    __syncthreads();
    if (tid == 0) {
        const float wgt = (bi == bj) ? 1.0f : 2.0f;  // off-diag covers transpose
        const float ta = (red[0] + red[1] + red[2] + red[3]) * wgt;
        const float tp = (red[4] + red[5] + red[6] + red[7]) * wgt;
        atomicAdd(&ws[0], (double)ta);
        atomicAdd(&ws[1], (double)tp);
        __threadfence();
        unsigned* ctr = (unsigned*)(ws + 2);
        if (atomicAdd(ctr, 1u) == NTRI - 1) {     // last live tile: finalize
            __threadfence();
            const double nom = atomicAdd(&ws[1], 0.0);
            const double den = atomicAdd(&ws[0], 0.0) - nom;
            out[0] = (float)(-log(nom / den) / (double)NROWS);
        }
    }
}

extern "C" void kernel_launch(void* const* d_in, const int* in_sizes, int n_in,
                              void* d_out, int out_size, void* d_ws, size_t ws_size,
                              hipStream_t stream) {
    const float* emb_i = (const float*)d_in[0];
    const float* emb_j = (const float*)d_in[1];
    float* out = (float*)d_out;
    double* ws = (double*)d_ws;                                   // accums + counter
    unsigned short* rep = (unsigned short*)((char*)d_ws + 256);   // bf16 [8192][512]

    hipLaunchKernelGGL(normalize_kernel, dim3(NROWS / 4), dim3(256), 0, stream,
                       emb_i, emb_j, rep, ws);
    hipLaunchKernelGGL(gram_kernel, dim3(NT, NT), dim3(256), 0, stream, rep, ws, out);
}